// Round 2
// baseline (493.475 us; speedup 1.0000x reference)
//
#include <hip/hip_runtime.h>

#define NBATCH 4
#define NPTS   16384
#define NQ     4096
#define NCH    64
#define K      32
#define CHOUT  67   // 3 + NCH

typedef float v2f __attribute__((ext_vector_type(2)));

// Packed fp32 ops via asm: exact rn rounding, no contraction possible.
__device__ __forceinline__ v2f pk_add(v2f a, v2f b) {
    v2f d; asm("v_pk_add_f32 %0, %1, %2" : "=v"(d) : "v"(a), "v"(b)); return d;
}
__device__ __forceinline__ v2f pk_mul(v2f a, v2f b) {
    v2f d; asm("v_pk_mul_f32 %0, %1, %2" : "=v"(d) : "v"(a), "v"(b)); return d;
}

// ---------------------------------------------------------------------------
// Kernel 1: brute-force exact top-32 KNN + centered-xyz channels.
// block = 256 (4 waves), QPW=2 queries per wave, QPB=8 per block, grid 2048
// (6 blocks/CU at 24 KB LDS -> 75% occupancy ceiling). SoA LDS tiles; packed
// fp32 distance math (2 points/lane/inst). Distances computed as
// ((p-q)x^2 + (p-q)y^2) + (p-q)z^2 with rn mul/add -> bit-identical to the
// reference's (q-p) version since squaring kills the sign.
// Top-32 list distributed across lanes 0..31, sorted by (dist, idx); candidates
// processed in ascending point index so top_k tie semantics match exactly.
// ---------------------------------------------------------------------------
constexpr int TILE = 2048;
constexpr int QPW  = 2;
constexpr int QPB  = 8;

__global__ __launch_bounds__(256) void knn_kernel(
    const float* __restrict__ xyz,
    const float* __restrict__ new_xyz,
    int*   __restrict__ out_idx,
    float* __restrict__ out)
{
    __shared__ float sx[TILE], sy[TILE], sz[TILE];   // 24 KB SoA

    const int tid  = threadIdx.x;
    const int lane = tid & 63;
    const int wave = tid >> 6;
    const int b    = blockIdx.x >> 9;                  // 512 blocks per batch
    const int q0   = (blockIdx.x & 511) * QPB + wave * QPW;

    const float* xb = xyz + (size_t)b * NPTS * 3;

    // Negated query coords (wave-uniform -> SGPR), plus broadcast pairs.
    float nqx[QPW], nqy[QPW], nqz[QPW];
    v2f nqx2[QPW], nqy2[QPW], nqz2[QPW];
#pragma unroll
    for (int j = 0; j < QPW; ++j) {
        const int base = ((b * NQ) + q0 + j) * 3;
        nqx[j] = __int_as_float(__builtin_amdgcn_readfirstlane(__float_as_int(-new_xyz[base + 0])));
        nqy[j] = __int_as_float(__builtin_amdgcn_readfirstlane(__float_as_int(-new_xyz[base + 1])));
        nqz[j] = __int_as_float(__builtin_amdgcn_readfirstlane(__float_as_int(-new_xyz[base + 2])));
        nqx2[j] = (v2f){nqx[j], nqx[j]};
        nqy2[j] = (v2f){nqy[j], nqy[j]};
        nqz2[j] = (v2f){nqz[j], nqz[j]};
    }

    float ld[QPW]; int li[QPW]; float T[QPW];
#pragma unroll
    for (int j = 0; j < QPW; ++j) {
        ld[j] = __int_as_float(0x7f800000);   // +inf
        li[j] = 0x7fffffff;
        T[j]  = __int_as_float(0x7f800000);
    }

    for (int t0 = 0; t0 < NPTS; t0 += TILE) {
        __syncthreads();
        for (int i = tid; i < TILE; i += 256) {        // AoS global -> SoA LDS
            const float* s = xb + (size_t)(t0 + i) * 3;
            sx[i] = s[0]; sy[i] = s[1]; sz[i] = s[2];
        }
        __syncthreads();

        for (int ii = 0; ii < TILE / 2; ii += 64) {
            const int i = ii + lane;                   // this lane's point pair
            const v2f px2 = *(const v2f*)(sx + 2 * i);
            const v2f py2 = *(const v2f*)(sy + 2 * i);
            const v2f pz2 = *(const v2f*)(sz + 2 * i);
            const int ibase = t0 + 2 * ii;             // wave-uniform
#pragma unroll
            for (int j = 0; j < QPW; ++j) {
                const v2f dx = pk_add(px2, nqx2[j]);
                const v2f dy = pk_add(py2, nqy2[j]);
                const v2f dz = pk_add(pz2, nqz2[j]);
                const v2f d2 = pk_add(pk_add(pk_mul(dx, dx), pk_mul(dy, dy)),
                                      pk_mul(dz, dz));
                unsigned long long m0 = __ballot(d2.x < T[j]);
                unsigned long long m1 = __ballot(d2.y < T[j]);
                while (m0 | m1) {
                    const int c0 = m0 ? (int)__builtin_ctzll(m0) : 64;
                    const int c1 = m1 ? (int)__builtin_ctzll(m1) : 64;
                    const bool lo = c0 <= c1;          // lo has smaller index at same lane
                    const int c = lo ? c0 : c1;
                    if (lo) m0 &= m0 - 1; else m1 &= m1 - 1;
                    const int blo = __builtin_amdgcn_readlane(__float_as_int(d2.x), c);
                    const int bhi = __builtin_amdgcn_readlane(__float_as_int(d2.y), c);
                    const float dn = __int_as_float(lo ? blo : bhi);
                    const int cand = ibase + 2 * c + (lo ? 0 : 1);
                    if (dn < T[j]) {                   // re-check vs freshest threshold
                        unsigned long long sh = __ballot(ld[j] > dn) & 0xffffffffull;
                        const int p = (int)__builtin_ctzll(sh);   // insert position
                        const float pd = __shfl_up(ld[j], 1);
                        const int   pi = __shfl_up(li[j], 1);
                        if ((sh >> lane) & 1) { ld[j] = pd; li[j] = pi; }
                        if (lane == p)        { ld[j] = dn; li[j] = cand; }
                        T[j] = __int_as_float(__builtin_amdgcn_readlane(__float_as_int(ld[j]), 31));
                    }
                }
            }
        }
    }

    // Epilogue: write idx + centered xyz channels (0..2).
#pragma unroll
    for (int j = 0; j < QPW; ++j) {
        if (lane < K) {
            const int q   = q0 + j;
            const int idx = li[j];
            out_idx[((size_t)(b * NQ) + q) * K + lane] = idx;
            const float px = xb[idx * 3 + 0];
            const float py = xb[idx * 3 + 1];
            const float pz = xb[idx * 3 + 2];
            const size_t plane = (size_t)NQ * K;
            const size_t o = (((size_t)b * CHOUT + 0) * NQ + q) * K + lane;
            out[o]             = __fadd_rn(px, nqx[j]);   // == px - qx, exact
            out[o + plane]     = __fadd_rn(py, nqy[j]);
            out[o + 2 * plane] = __fadd_rn(pz, nqz[j]);
        }
    }
}

// ---------------------------------------------------------------------------
// Kernel 2: feature gather, channels 3..66.
// grid = B x NCH = 256 blocks, block = 1024. Each block stages ONE feature
// row (64 KB) into LDS once, then gathers all 4096x32 entries for it:
// int4 idx loads + 4 random LDS reads + float4 coalesced stores.
// Feature HBM/L2 traffic: 16 MB total (vs 131 MB in v1).
// ---------------------------------------------------------------------------
__global__ __launch_bounds__(1024) void gather_kernel(
    const float* __restrict__ features,
    const int*   __restrict__ idx,
    float* __restrict__ out)
{
    __shared__ __align__(16) float row[NPTS];   // 64 KB

    const int tid = threadIdx.x;
    const int b   = blockIdx.x >> 6;
    const int c   = blockIdx.x & 63;

    const float4* src = (const float4*)(features + ((size_t)(b * NCH + c)) * NPTS);
    for (int k2 = tid; k2 < NPTS / 4; k2 += 1024) ((float4*)row)[k2] = src[k2];
    __syncthreads();

    const int4* gi = (const int4*)(idx + (size_t)b * NQ * K);
    float4* dst = (float4*)(out + ((size_t)(b * CHOUT + 3 + c)) * NQ * K);
#pragma unroll 4
    for (int p = tid; p < NQ * K / 4; p += 1024) {
        const int4 ii = gi[p];
        float4 o;
        o.x = row[ii.x]; o.y = row[ii.y]; o.z = row[ii.z]; o.w = row[ii.w];
        dst[p] = o;
    }
}

extern "C" void kernel_launch(void* const* d_in, const int* in_sizes, int n_in,
                              void* d_out, int out_size, void* d_ws, size_t ws_size,
                              hipStream_t stream) {
    const float* xyz      = (const float*)d_in[0];
    const float* new_xyz  = (const float*)d_in[1];
    const float* features = (const float*)d_in[2];
    float* out    = (float*)d_out;
    int*   ws_idx = (int*)d_ws;   // 4*4096*32*4 = 2 MB scratch

    knn_kernel<<<dim3(NBATCH * (NQ / QPB)), dim3(256), 0, stream>>>(xyz, new_xyz, ws_idx, out);
    gather_kernel<<<dim3(NBATCH * NCH), dim3(1024), 0, stream>>>(features, ws_idx, out);
}